// Round 7
// baseline (622.678 us; speedup 1.0000x reference)
//
#include <hip/hip_runtime.h>

#define SLOPE 0.01f
#define BN_EPS 1e-5f

typedef __attribute__((ext_vector_type(8))) short short8;
typedef __attribute__((ext_vector_type(4))) float f32x4;

static constexpr int D1 = 32, H1 = 96, W1_ = 96;
static constexpr int HW1 = H1 * W1_, DHW1 = D1 * HW1;        // 294912
static constexpr int D0 = 16, H0 = 48, W0 = 48;
static constexpr int HW0 = H0 * W0, DHW0 = D0 * HW0;         // 36864

// padded geometries (y/x halo of 1, plus one trailing all-zero "trash" z-plane)
static constexpr int FP_PLPTS = 98 * 98;            // fine padded plane pts
static constexpr int CP_PLPTS = 50 * 50;            // coarse padded plane pts
static constexpr int FP_ELEMS = 33 * FP_PLPTS * 64; // fine padded buffer elems

__device__ __forceinline__ short f2bf(float f) {
    unsigned u = __builtin_bit_cast(unsigned, f);
    unsigned r = (u + 0x7fffu + ((u >> 16) & 1u)) >> 16;
    return (short)r;
}
__device__ __forceinline__ float bf2f(short s) {
    unsigned u = ((unsigned)(unsigned short)s) << 16;
    return __builtin_bit_cast(float, u);
}
__device__ __forceinline__ int pidx_fine(int s) {
    int z = s / HW1; int r = s - z * HW1; int y = r / W1_; int x = r - y * W1_;
    return z * FP_PLPTS + (y + 1) * 98 + (x + 1);
}
__device__ __forceinline__ int pidx_coarse(int s) {
    int z = s / HW0; int r = s - z * HW0; int y = r / W0; int x = r - y * W0;
    return z * CP_PLPTS + (y + 1) * 50 + (x + 1);
}
__device__ __forceinline__ void gload16(const void* g, void* l) {
    __builtin_amdgcn_global_load_lds(
        (const __attribute__((address_space(1))) void*)g,
        (__attribute__((address_space(3))) void*)l, 16, 0, 0);
}

// ---------------------------------------------------------------------------
__global__ __launch_bounds__(256)
void to_cl_pad128(const float* __restrict__ in, short* __restrict__ out)
{
    __shared__ float t[64][65];
    const int s0 = blockIdx.x * 64, c0 = blockIdx.y * 64;
    const int tid = threadIdx.x;
    {
        const int cpr = tid >> 2, ch = tid & 3;
        const float4* ip = (const float4*)(in + (size_t)(c0 + cpr) * DHW0 + s0 + ch * 16);
        #pragma unroll
        for (int i = 0; i < 4; ++i) {
            float4 v = ip[i]; int sb = ch * 16 + i * 4;
            t[sb][cpr] = v.x; t[sb + 1][cpr] = v.y; t[sb + 2][cpr] = v.z; t[sb + 3][cpr] = v.w;
        }
    }
    __syncthreads();
    {
        const int spr = tid >> 2, cc = (tid & 3) * 16;
        short8 o0, o1;
        #pragma unroll
        for (int q = 0; q < 8; ++q) { o0[q] = f2bf(t[spr][cc + q]); o1[q] = f2bf(t[spr][cc + 8 + q]); }
        const int p = pidx_coarse(s0 + spr);
        short* op = out + (size_t)p * 128 + c0 + cc;
        *(short8*)op = o0;
        *(short8*)(op + 8) = o1;
    }
}

__global__ __launch_bounds__(256)
void to_cl_bf16(const float* __restrict__ in, short* __restrict__ out, int S)
{
    __shared__ float t[64][65];
    const int s0 = blockIdx.x * 64;
    const int tid = threadIdx.x;
    {
        const int cpr = tid >> 2, ch = tid & 3;
        const float4* ip = (const float4*)(in + (size_t)cpr * S + s0 + ch * 16);
        #pragma unroll
        for (int i = 0; i < 4; ++i) {
            float4 v = ip[i]; int sb = ch * 16 + i * 4;
            t[sb][cpr] = v.x; t[sb + 1][cpr] = v.y; t[sb + 2][cpr] = v.z; t[sb + 3][cpr] = v.w;
        }
    }
    __syncthreads();
    {
        const int spr = tid >> 2, cc = (tid & 3) * 16;
        short8 o0, o1;
        #pragma unroll
        for (int q = 0; q < 8; ++q) { o0[q] = f2bf(t[spr][cc + q]); o1[q] = f2bf(t[spr][cc + 8 + q]); }
        short* op = out + (size_t)(s0 + spr) * 64 + cc;
        *(short8*)op = o0;
        *(short8*)(op + 8) = o1;
    }
}

__global__ __launch_bounds__(256)
void prep_w(const float* __restrict__ w, short* __restrict__ dst, int CIN, int KSZ)
{
    int i = blockIdx.x * 256 + threadIdx.x;
    int n = KSZ * 64 * CIN;
    if (i >= n) return;
    int t = i / (64 * CIN); int r = i % (64 * CIN); int o = r / CIN; int ci = r % CIN;
    dst[i] = f2bf(w[(size_t)(o * CIN + ci) * KSZ + t]);
}

__global__ void finalize_stats(const float* __restrict__ stats, const float* __restrict__ g,
                               const float* __restrict__ b, float invN, float* __restrict__ aff)
{
    int c = threadIdx.x;
    float m = stats[c] * invN;
    float var = stats[64 + c] * invN - m * m;
    float rstd = rsqrtf(var + BN_EPS);
    float sc = g[c] * rstd;
    aff[c] = sc;
    aff[64 + c] = b[c] - m * sc;
}

template<int MODE> // 1 = fine, 2 = coarse
__global__ __launch_bounds__(256)
void affine_pad(short* __restrict__ buf, const float* __restrict__ aff, int n8)
{
    int i = blockIdx.x * 256 + threadIdx.x;
    if (i >= n8) return;
    int s = i >> 3, cb = (i & 7) * 8;
    int p = (MODE == 1) ? pidx_fine(s) : pidx_coarse(s);
    short* ptr = buf + (size_t)p * 64 + cb;
    short8 v = *(const short8*)ptr;
    short8 o;
    #pragma unroll
    for (int q = 0; q < 8; ++q) {
        int c = cb + q;
        o[q] = f2bf(bf2f(v[q]) * aff[c] + aff[64 + c]);
    }
    *(short8*)ptr = o;
}

__global__ __launch_bounds__(256)
void final_out(const short* __restrict__ in, float* __restrict__ out, const float* __restrict__ aff)
{
    __shared__ float t[64][65];
    const int s0 = blockIdx.x * 64;
    const int tid = threadIdx.x;
    {
        const int spr = tid >> 2, ch = tid & 3;
        const short8* ip = (const short8*)(in + (size_t)(s0 + spr) * 64 + ch * 16);
        short8 v0 = ip[0], v1 = ip[1];
        #pragma unroll
        for (int q = 0; q < 8; ++q) { int c = ch * 16 + q;     t[spr][c] = bf2f(v0[q]) * aff[c] + aff[64 + c]; }
        #pragma unroll
        for (int q = 0; q < 8; ++q) { int c = ch * 16 + 8 + q; t[spr][c] = bf2f(v1[q]) * aff[c] + aff[64 + c]; }
    }
    __syncthreads();
    {
        const int c = tid >> 2, sc = (tid & 3) * 16;
        #pragma unroll
        for (int i = 0; i < 4; ++i) {
            float4 w;
            w.x = t[sc + 4 * i][c]; w.y = t[sc + 4 * i + 1][c];
            w.z = t[sc + 4 * i + 2][c]; w.w = t[sc + 4 * i + 3][c];
            *(float4*)(out + (size_t)c * DHW1 + s0 + sc + 4 * i) = w;
        }
    }
}

// zero the y/x halo edges of each plane of a padded channels-last buffer
template<int GH, int GW, int CIN>
__global__ __launch_bounds__(256)
void zero_halo(short* __restrict__ buf)
{
    constexpr int PPW = GW + 2, PLP = (GH + 2) * PPW, CPR = CIN / 8;
    constexpr int NCHK = (2 * PPW + 2 * GH) * CPR;
    const int pl = blockIdx.x;
    const short8 z8 = {0, 0, 0, 0, 0, 0, 0, 0};
    for (int i = threadIdx.x; i < NCHK; i += 256) {
        int p = i / CPR, c = i % CPR;
        int y, x;
        if (p < PPW) { y = 0; x = p; }
        else if (p < 2 * PPW) { y = GH + 1; x = p - PPW; }
        else { int q = p - 2 * PPW; y = 1 + (q >> 1); x = (q & 1) ? (GW + 1) : 0; }
        *(short8*)(buf + ((size_t)pl * PLP + y * PPW + x) * CIN + c * 8) = z8;
    }
}

// ---------------------------------------------------------------------------
// kw-bundled LDS-staged implicit-GEMM conv (T3+T4+T5).
// Phases = KD*KH (kw always 3-bundled, PW=1). Per phase: stage ONE contiguous
// padded A-segment (covers M-tile + x-shift +-1; halo zeros give correct kw
// edges), double-buffered via global_load_lds + counted vmcnt; B fragments
// loaded per-phase from global into VGPRs (L1/L2-resident, fenced inside the
// phase by sched_barrier). 3 kw-taps read +-1-shifted rows from the segment.
template<int MG, int CIN, int KD, int KH, int PD, int PH,
         int GD, int GH, int GW, int OUTMODE, bool STATS>
__global__ __launch_bounds__(256, 2)
void convmm6(const short* __restrict__ A, const short* __restrict__ Wt,
             short* __restrict__ Out, float* __restrict__ stats)
{
    constexpr int MR   = 64 * MG;
    constexpr int PPW  = GW + 2;
    constexpr int PLP  = (GH + 2) * PPW;
    constexpr int HWg  = GH * GW;
    constexpr int CPR  = CIN / 8;                // 16B chunks per point
    constexpr int KCN  = CIN / 32;
    constexpr int LSEG = (MG == 4) ? 288 : 80;   // staged segment points (>= span+2)
    constexpr int PPI  = 64 / CPR;               // points per gload instr
    constexpr int API  = LSEG / (4 * PPI);       // gload instrs per wave (9 fine, 5 coarse)
    constexpr int ABYTES = LSEG * CIN * 2;       // 36864 fine, 20480 coarse
    constexpr int P    = KD * KH;                // phases

    __shared__ __align__(16) char smem[2 * ABYTES];

    const int tid = threadIdx.x, lane = tid & 63, wave = tid >> 6;
    const int rl = lane & 15, kg = lane >> 4;

    // XCD-aware bijective swizzle (grids are multiples of 8)
    const int nwg = gridDim.x;
    const int bid = blockIdx.x;
    const int bswz = (nwg & 7) ? bid : ((bid & 7) * (nwg >> 3) + (bid >> 3));
    const int s0 = bswz * MR;                    // M-tile never crosses a z-plane
    const int z0 = s0 / HWg;
    const int rem0 = s0 - z0 * HWg;
    const int yx0 = (rem0 / GW + 1) * PPW + (rem0 % GW + 1);

    // staging constants: instr i covers segment pts [(wave*API+i)*PPI, +PPI)
    int jp_[API], cs_[API];
    #pragma unroll
    for (int i = 0; i < API; ++i) {
        jp_[i] = (wave * API + i) * PPI + lane / CPR;
        cs_[i] = (lane & (CPR - 1)) ^ (jp_[i] & 7);
    }

    // per-mg segment row index (j = yx(s_lane) - yx0; tap kw reads j+kw)
    int jm[MG];
    #pragma unroll
    for (int mg = 0; mg < MG; ++mg) {
        int s = s0 + wave * (16 * MG) + mg * 16 + rl;
        int rm = s - z0 * HWg;
        jm[mg] = (rm / GW + 1) * PPW + (rm % GW + 1) - yx0;
    }

    auto stage = [&](int bsel, int kd, int kh) {
        int zp = z0 + kd - PD;
        size_t P0 = ((unsigned)zp < (unsigned)GD)
            ? (size_t)zp * PLP + yx0 + (kh - PH) * PPW - 1
            : (size_t)GD * PLP;                           // trash plane (zeros)
        #pragma unroll
        for (int i = 0; i < API; ++i) {
            const short* src = A + (P0 + jp_[i]) * CIN + cs_[i] * 8;
            void* dst = smem + bsel * ABYTES + (wave * API + i) * 1024 + lane * 16;
            gload16(src, dst);
        }
    };

    f32x4 acc[MG][4];
    #pragma unroll
    for (int mg = 0; mg < MG; ++mg)
        #pragma unroll
        for (int ng = 0; ng < 4; ++ng)
            acc[mg][ng] = (f32x4){0.f, 0.f, 0.f, 0.f};

    auto comp = [&](int bsel, int T0) {
        const char* ab = smem + bsel * ABYTES;
        #pragma unroll
        for (int kw = 0; kw < 3; ++kw) {
            const short* wt = Wt + (size_t)(T0 + kw) * 64 * CIN;
            short8 bv[KCN][4];
            #pragma unroll
            for (int kc = 0; kc < KCN; ++kc)
                #pragma unroll
                for (int ng = 0; ng < 4; ++ng)
                    bv[kc][ng] = *(const short8*)(wt + (ng * 16 + rl) * CIN + (kc * 4 + kg) * 8);
            #pragma unroll
            for (int kc = 0; kc < KCN; ++kc) {
                short8 av[MG];
                #pragma unroll
                for (int mg = 0; mg < MG; ++mg) {
                    const int j = jm[mg] + kw;
                    av[mg] = *(const short8*)(ab + j * (CIN * 2) + (((kc * 4 + kg) ^ (j & 7)) << 4));
                }
                __builtin_amdgcn_s_setprio(1);
                #pragma unroll
                for (int mg = 0; mg < MG; ++mg)
                    #pragma unroll
                    for (int ng = 0; ng < 4; ++ng)
                        acc[mg][ng] = __builtin_amdgcn_mfma_f32_16x16x32_bf16(av[mg], bv[kc][ng], acc[mg][ng], 0, 0, 0);
                __builtin_amdgcn_s_setprio(0);
            }
        }
    };

    // prologue: stage phase 0 (kd=0, kh=0)
    stage(0, 0, 0);

    #pragma unroll
    for (int p = 0; p < P; ++p) {
        const int kd = p / KH, kh = p % KH;
        if (p + 1 < P) {
            stage((p + 1) & 1, (p + 1) / KH, (p + 1) % KH);
            asm volatile("s_waitcnt vmcnt(%0)" :: "i"(API) : "memory");
        } else {
            asm volatile("s_waitcnt vmcnt(0)" ::: "memory");
        }
        __builtin_amdgcn_s_barrier();
        __builtin_amdgcn_sched_barrier(0);
        comp(p & 1, (kd * KH + kh) * 3);
        asm volatile("s_waitcnt lgkmcnt(0)" ::: "memory");
        __builtin_amdgcn_sched_barrier(0);
        __builtin_amdgcn_s_barrier();
    }

    // epilogue: tile aliases A buffer 0; red aliases A buffer 1
    short (*tile)[64] = (short(*)[64])smem;
    float* red = (float*)(smem + ABYTES);

    #pragma unroll
    for (int mg = 0; mg < MG; ++mg)
        #pragma unroll
        for (int ng = 0; ng < 4; ++ng)
            #pragma unroll
            for (int j = 0; j < 4; ++j) {
                float v = acc[mg][ng][j];
                if (STATS) v = (v >= 0.f) ? v : SLOPE * v;
                tile[wave * (16 * MG) + mg * 16 + kg * 4 + j][ng * 16 + rl] = f2bf(v);
            }
    __syncthreads();

    #pragma unroll
    for (int i = 0; i < MR / 32; ++i) {
        const int chunk = i * 256 + tid;
        const int r = chunk >> 3, cc = (chunk & 7) * 8;
        const int s = s0 + r;
        size_t o;
        if (OUTMODE == 0)      o = (size_t)s * 64 + cc;
        else if (OUTMODE == 1) o = (size_t)pidx_fine(s) * 64 + cc;
        else                   o = (size_t)pidx_coarse(s) * 64 + cc;
        *(short8*)(Out + o) = *(const short8*)&tile[r][cc];
    }

    if (STATS) {
        float s1 = 0.f, s2 = 0.f;
        const int col = tid & 63, rg = tid >> 6;
        #pragma unroll 4
        for (int r = rg * (MR / 4); r < (rg + 1) * (MR / 4); ++r) {
            float v = bf2f(tile[r][col]); s1 += v; s2 += v * v;
        }
        red[rg * 64 + col] = s1;
        red[256 + rg * 64 + col] = s2;
        __syncthreads();
        if (tid < 64) {
            float a = red[tid] + red[64 + tid] + red[128 + tid] + red[192 + tid];
            float b = red[256 + tid] + red[320 + tid] + red[384 + tid] + red[448 + tid];
            atomicAdd(&stats[tid], a);
            atomicAdd(&stats[64 + tid], b);
        }
    }
}

// ---------------------------------------------------------------------------
// Transposed conv by output-parity class (round-4/6 proven version).
__global__ __launch_bounds__(256, 2)
void tconv_cls(const short* __restrict__ Y, const short* __restrict__ Wt,
               const short* __restrict__ SK, short* __restrict__ Out)
{
    const int cls = blockIdx.y;
    const int pz = (cls >> 2) & 1, py = (cls >> 1) & 1, px = cls & 1;
    const int tid = threadIdx.x, lane = tid & 63, wave = tid >> 6;
    const int rl = lane & 15, kg = lane >> 4;
    const int row0 = blockIdx.x * 256;

    int zin0[4], zin1[4];
    #pragma unroll
    for (int mg = 0; mg < 4; ++mg) {
        int s = row0 + wave * 64 + mg * 16 + rl;
        int zc = s / HW0; int r = s - zc * HW0; int yc = r / W0; int xc = r - yc * W0;
        int ib = ((yc + 1) * 50 + (xc + 1)) * 64 + kg * 8;
        zin0[mg] = zc * (CP_PLPTS * 64) + ib;
        zin1[mg] = ((zc + 1 < 16) ? zc + 1 : 16) * (CP_PLPTS * 64) + ib;
    }
    const int boff = rl * 64 + kg * 8;

    f32x4 acc[4][4];
    #pragma unroll
    for (int mg = 0; mg < 4; ++mg)
        #pragma unroll
        for (int ng = 0; ng < 4; ++ng)
            acc[mg][ng] = (f32x4){0.f, 0.f, 0.f, 0.f};

    for (int a = 0; a <= pz; ++a) {
        const int kd = pz ? 2 * a : 1;
        for (int b = 0; b <= py; ++b) {
            const int kh = py ? 2 * b : 1;
            for (int c = 0; c <= px; ++c) {
                const int kw = px ? 2 * c : 1;
                const int t = kd * 9 + kh * 3 + kw;
                const int dlt = (b * 50 + c) * 64;
                int ao[4];
                #pragma unroll
                for (int mg = 0; mg < 4; ++mg)
                    ao[mg] = (a ? zin1[mg] : zin0[mg]) + dlt;
                #pragma unroll
                for (int kc = 0; kc < 2; ++kc) {
                    short8 av[4], bv[4];
                    #pragma unroll
                    for (int mg = 0; mg < 4; ++mg)
                        av[mg] = *(const short8*)(Y + ao[mg] + kc * 32);
                    #pragma unroll
                    for (int ng = 0; ng < 4; ++ng)
                        bv[ng] = *(const short8*)(Wt + (t * 64 + ng * 16) * 64 + boff + kc * 32);
                    #pragma unroll
                    for (int mg = 0; mg < 4; ++mg)
                        #pragma unroll
                        for (int ng = 0; ng < 4; ++ng)
                            acc[mg][ng] = __builtin_amdgcn_mfma_f32_16x16x32_bf16(av[mg], bv[ng], acc[mg][ng], 0, 0, 0);
                }
            }
        }
    }

    __shared__ short tile[256][72];
    #pragma unroll
    for (int mg = 0; mg < 4; ++mg)
        #pragma unroll
        for (int ng = 0; ng < 4; ++ng)
            #pragma unroll
            for (int j = 0; j < 4; ++j)
                tile[wave * 64 + mg * 16 + kg * 4 + j][ng * 16 + rl] = f2bf(acc[mg][ng][j]);
    __syncthreads();

    #pragma unroll
    for (int i = 0; i < 8; ++i) {
        int chunk = i * 256 + tid;
        int r = chunk >> 3, cc = (chunk & 7) * 8;
        int sl = row0 + r;
        int zc = sl / HW0; int rr = sl - zc * HW0; int yc = rr / W0; int xc = rr - yc * W0;
        int z = 2 * zc + pz, y = 2 * yc + py, x = 2 * xc + px;
        size_t so = (size_t)((z * H1 + y) * W1_ + x) * 64 + cc;
        size_t po = (size_t)(z * FP_PLPTS + (y + 1) * 98 + (x + 1)) * 64 + cc;
        short8 v = *(const short8*)&tile[r][cc];
        short8 skv = *(const short8*)(SK + so);
        short8 o;
        #pragma unroll
        for (int q = 0; q < 8; ++q) o[q] = f2bf(bf2f(v[q]) + bf2f(skv[q]));
        *(short8*)(Out + po) = o;
    }
}

// ---------------------------------------------------------------------------
extern "C" void kernel_launch(void* const* d_in, const int* in_sizes, int n_in,
                              void* d_out, int out_size, void* d_ws, size_t ws_size,
                              hipStream_t stream)
{
    const float* x       = (const float*)d_in[0];
    const float* skip    = (const float*)d_in[1];
    const float* w_trans = (const float*)d_in[2];
    const float* g_t     = (const float*)d_in[3];
    const float* b_t     = (const float*)d_in[4];
    const float* w_up    = (const float*)d_in[5];
    const float* w1      = (const float*)d_in[6];
    const float* g1      = (const float*)d_in[7];
    const float* b1      = (const float*)d_in[8];
    const float* w2      = (const float*)d_in[9];
    const float* g2      = (const float*)d_in[10];
    const float* b2      = (const float*)d_in[11];
    const float* w3      = (const float*)d_in[12];
    const float* g3      = (const float*)d_in[13];
    const float* b3      = (const float*)d_in[14];
    float* out = (float*)d_out;

    char* ws = (char*)d_ws;
    short* PadA = (short*)ws;
    short* PadB = (short*)(ws + (size_t)FP_ELEMS * 2);
    float* stats = (float*)(ws + (size_t)FP_ELEMS * 4);

    float* st0 = stats;       float* af0 = stats + 512;
    float* st1 = stats + 128; float* af1 = stats + 512 + 128;
    float* st2 = stats + 256; float* af2 = stats + 512 + 256;
    float* st3 = stats + 384; float* af3 = stats + 512 + 384;

    char* ob = (char*)d_out;
    short* X0  = (short*)ob;                       // coarse padded 128ch
    short* Y0  = (short*)(ob + 10880000);          // coarse padded 64ch
    short* SKb = (short*)(ob + 16320000);          // compact fine skip
    short* wt_t  = (short*)(ob + 54068736);
    short* wt_up = wt_t + 221184;
    short* wt_1  = wt_up + 110592;
    short* wt_2  = wt_1 + 36864;
    short* wt_3  = wt_2 + 36864;

    // halo-only zeroing (edges via kernel, trash planes + stats via small memsets)
    zero_halo<96, 96, 64><<<33, 256, 0, stream>>>(PadA);
    zero_halo<96, 96, 64><<<33, 256, 0, stream>>>(PadB);
    zero_halo<48, 48, 128><<<17, 256, 0, stream>>>(X0);
    zero_halo<48, 48, 64><<<17, 256, 0, stream>>>(Y0);
    hipMemsetAsync((char*)PadA + (size_t)32 * FP_PLPTS * 128, 0, FP_PLPTS * 128, stream);
    hipMemsetAsync((char*)PadB + (size_t)32 * FP_PLPTS * 128, 0, FP_PLPTS * 128, stream);
    hipMemsetAsync((char*)X0 + (size_t)16 * CP_PLPTS * 256, 0, CP_PLPTS * 256, stream);
    hipMemsetAsync((char*)Y0 + (size_t)16 * CP_PLPTS * 128, 0, CP_PLPTS * 128, stream);
    hipMemsetAsync(stats, 0, 2048, stream);

    // weight repacks
    prep_w<<<(27 * 64 * 128 + 255) / 256, 256, 0, stream>>>(w_trans, wt_t, 128, 27);
    prep_w<<<(27 * 64 * 64 + 255) / 256, 256, 0, stream>>>(w_up, wt_up, 64, 27);
    prep_w<<<(9 * 64 * 64 + 255) / 256, 256, 0, stream>>>(w1, wt_1, 64, 9);
    prep_w<<<(9 * 64 * 64 + 255) / 256, 256, 0, stream>>>(w2, wt_2, 64, 9);
    prep_w<<<(27 * 64 * 64 + 255) / 256, 256, 0, stream>>>(w3, wt_3, 64, 27);

    // input transposes
    to_cl_pad128<<<dim3(DHW0 / 64, 2), 256, 0, stream>>>(x, X0);
    to_cl_bf16<<<DHW1 / 64, 256, 0, stream>>>(skip, SKb, DHW1);

    // stage A: subm 3x3x3 CIN=128 coarse -> Y0pad (raw lrelu) + stats  [9 phases]
    convmm6<1, 128, 3, 3, 1, 1, 16, 48, 48, 2, true>
        <<<DHW0 / 64, 256, 0, stream>>>(X0, wt_t, Y0, st0);
    finalize_stats<<<1, 64, 0, stream>>>(st0, g_t, b_t, 1.f / DHW0, af0);
    affine_pad<2><<<(DHW0 * 8 + 255) / 256, 256, 0, stream>>>(Y0, af0, DHW0 * 8);

    // stage B: transposed conv by parity class + skip -> PadA
    tconv_cls<<<dim3(DHW0 / 256, 8), 256, 0, stream>>>(Y0, wt_up, SKb, PadA);

    // stage C: conv (1,3,3) pad (0,1,1) -> PadB + stats   [3 phases]
    convmm6<4, 64, 1, 3, 0, 1, 32, 96, 96, 1, true>
        <<<DHW1 / 256, 256, 0, stream>>>(PadA, wt_1, PadB, st1);
    finalize_stats<<<1, 64, 0, stream>>>(st1, g1, b1, 1.f / DHW1, af1);
    affine_pad<1><<<(DHW1 * 8 + 255) / 256, 256, 0, stream>>>(PadB, af1, DHW1 * 8);

    // stage D: conv (3,1,3) pad (1,0,1) -> PadA + stats   [3 phases]
    convmm6<4, 64, 3, 1, 1, 0, 32, 96, 96, 1, true>
        <<<DHW1 / 256, 256, 0, stream>>>(PadB, wt_2, PadA, st2);
    finalize_stats<<<1, 64, 0, stream>>>(st2, g2, b2, 1.f / DHW1, af2);
    affine_pad<1><<<(DHW1 * 8 + 255) / 256, 256, 0, stream>>>(PadA, af2, DHW1 * 8);

    // stage E: conv (3,3,3) pad 1 -> PadB COMPACT + stats  [9 phases]
    convmm6<4, 64, 3, 3, 1, 1, 32, 96, 96, 0, true>
        <<<DHW1 / 256, 256, 0, stream>>>(PadA, wt_3, PadB, st3);
    finalize_stats<<<1, 64, 0, stream>>>(st3, g3, b3, 1.f / DHW1, af3);

    // final: aff3 + transpose to NCDHW fp32
    final_out<<<DHW1 / 64, 256, 0, stream>>>(PadB, out, af3);
}

// Round 8
// 410.157 us; speedup vs baseline: 1.5181x; 1.5181x over previous
//
#include <hip/hip_runtime.h>

#define SLOPE 0.01f
#define BN_EPS 1e-5f

typedef __attribute__((ext_vector_type(8))) short short8;
typedef __attribute__((ext_vector_type(4))) float f32x4;

static constexpr int D1 = 32, H1 = 96, W1_ = 96;
static constexpr int HW1 = H1 * W1_, DHW1 = D1 * HW1;        // 294912
static constexpr int D0 = 16, H0 = 48, W0 = 48;
static constexpr int HW0 = H0 * W0, DHW0 = D0 * HW0;         // 36864

static constexpr int FP_PLPTS = 98 * 98;            // fine padded plane pts
static constexpr int CP_PLPTS = 50 * 50;            // coarse padded plane pts
static constexpr int FP_ELEMS = 33 * FP_PLPTS * 64; // fine padded buffer elems

__device__ __forceinline__ short f2bf(float f) {
    unsigned u = __builtin_bit_cast(unsigned, f);
    unsigned r = (u + 0x7fffu + ((u >> 16) & 1u)) >> 16;
    return (short)r;
}
__device__ __forceinline__ float bf2f(short s) {
    unsigned u = ((unsigned)(unsigned short)s) << 16;
    return __builtin_bit_cast(float, u);
}
__device__ __forceinline__ int pidx_fine(int s) {
    int z = s / HW1; int r = s - z * HW1; int y = r / W1_; int x = r - y * W1_;
    return z * FP_PLPTS + (y + 1) * 98 + (x + 1);
}
__device__ __forceinline__ int pidx_coarse(int s) {
    int z = s / HW0; int r = s - z * HW0; int y = r / W0; int x = r - y * W0;
    return z * CP_PLPTS + (y + 1) * 50 + (x + 1);
}
__device__ __forceinline__ void gload16(const void* g, void* l) {
    __builtin_amdgcn_global_load_lds(
        (const __attribute__((address_space(1))) void*)g,
        (__attribute__((address_space(3))) void*)l, 16, 0, 0);
}

// ---------------------------------------------------------------------------
__global__ __launch_bounds__(256)
void to_cl_pad128(const float* __restrict__ in, short* __restrict__ out)
{
    __shared__ float t[64][65];
    const int s0 = blockIdx.x * 64, c0 = blockIdx.y * 64;
    const int tid = threadIdx.x;
    {
        const int cpr = tid >> 2, ch = tid & 3;
        const float4* ip = (const float4*)(in + (size_t)(c0 + cpr) * DHW0 + s0 + ch * 16);
        #pragma unroll
        for (int i = 0; i < 4; ++i) {
            float4 v = ip[i]; int sb = ch * 16 + i * 4;
            t[sb][cpr] = v.x; t[sb + 1][cpr] = v.y; t[sb + 2][cpr] = v.z; t[sb + 3][cpr] = v.w;
        }
    }
    __syncthreads();
    {
        const int spr = tid >> 2, cc = (tid & 3) * 16;
        short8 o0, o1;
        #pragma unroll
        for (int q = 0; q < 8; ++q) { o0[q] = f2bf(t[spr][cc + q]); o1[q] = f2bf(t[spr][cc + 8 + q]); }
        const int p = pidx_coarse(s0 + spr);
        short* op = out + (size_t)p * 128 + c0 + cc;
        *(short8*)op = o0;
        *(short8*)(op + 8) = o1;
    }
}

__global__ __launch_bounds__(256)
void to_cl_bf16(const float* __restrict__ in, short* __restrict__ out, int S)
{
    __shared__ float t[64][65];
    const int s0 = blockIdx.x * 64;
    const int tid = threadIdx.x;
    {
        const int cpr = tid >> 2, ch = tid & 3;
        const float4* ip = (const float4*)(in + (size_t)cpr * S + s0 + ch * 16);
        #pragma unroll
        for (int i = 0; i < 4; ++i) {
            float4 v = ip[i]; int sb = ch * 16 + i * 4;
            t[sb][cpr] = v.x; t[sb + 1][cpr] = v.y; t[sb + 2][cpr] = v.z; t[sb + 3][cpr] = v.w;
        }
    }
    __syncthreads();
    {
        const int spr = tid >> 2, cc = (tid & 3) * 16;
        short8 o0, o1;
        #pragma unroll
        for (int q = 0; q < 8; ++q) { o0[q] = f2bf(t[spr][cc + q]); o1[q] = f2bf(t[spr][cc + 8 + q]); }
        short* op = out + (size_t)(s0 + spr) * 64 + cc;
        *(short8*)op = o0;
        *(short8*)(op + 8) = o1;
    }
}

// merged weight repack: [o][ci][t] fp32 -> [t][o][ci] bf16, all 5 stages
__device__ __forceinline__ void rp(const float* __restrict__ w, short* __restrict__ dst,
                                   int CIN, int KSZ, int i)
{
    int t = i / (64 * CIN); int r = i % (64 * CIN); int o = r / CIN; int ci = r % CIN;
    dst[i] = f2bf(w[(size_t)(o * CIN + ci) * KSZ + t]);
}
__global__ __launch_bounds__(256)
void prep_all(const float* __restrict__ wt, const float* __restrict__ wu,
              const float* __restrict__ w1, const float* __restrict__ w2,
              const float* __restrict__ w3, short* dt, short* du,
              short* d1, short* d2, short* d3)
{
    int i = blockIdx.x * 256 + threadIdx.x;
    if (i < 221184) { rp(wt, dt, 128, 27, i); return; } i -= 221184;
    if (i < 110592) { rp(wu, du, 64, 27, i); return; } i -= 110592;
    if (i < 36864)  { rp(w1, d1, 64, 9, i);  return; } i -= 36864;
    if (i < 36864)  { rp(w2, d2, 64, 9, i);  return; } i -= 36864;
    if (i < 110592) rp(w3, d3, 64, 27, i);
}

__global__ void finalize_stats(const float* __restrict__ stats, const float* __restrict__ g,
                               const float* __restrict__ b, float invN, float* __restrict__ aff)
{
    int c = threadIdx.x;
    float m = stats[c] * invN;
    float var = stats[64 + c] * invN - m * m;
    float rstd = rsqrtf(var + BN_EPS);
    float sc = g[c] * rstd;
    aff[c] = sc;
    aff[64 + c] = b[c] - m * sc;
}

template<int MODE> // 1 = fine, 2 = coarse
__global__ __launch_bounds__(256)
void affine_pad(short* __restrict__ buf, const float* __restrict__ aff, int n8)
{
    int i = blockIdx.x * 256 + threadIdx.x;
    if (i >= n8) return;
    int s = i >> 3, cb = (i & 7) * 8;
    int p = (MODE == 1) ? pidx_fine(s) : pidx_coarse(s);
    short* ptr = buf + (size_t)p * 64 + cb;
    short8 v = *(const short8*)ptr;
    short8 o;
    #pragma unroll
    for (int q = 0; q < 8; ++q) {
        int c = cb + q;
        o[q] = f2bf(bf2f(v[q]) * aff[c] + aff[64 + c]);
    }
    *(short8*)ptr = o;
}

__global__ __launch_bounds__(256)
void final_out(const short* __restrict__ in, float* __restrict__ out, const float* __restrict__ aff)
{
    __shared__ float t[64][65];
    const int s0 = blockIdx.x * 64;
    const int tid = threadIdx.x;
    {
        const int spr = tid >> 2, ch = tid & 3;
        const short8* ip = (const short8*)(in + (size_t)(s0 + spr) * 64 + ch * 16);
        short8 v0 = ip[0], v1 = ip[1];
        #pragma unroll
        for (int q = 0; q < 8; ++q) { int c = ch * 16 + q;     t[spr][c] = bf2f(v0[q]) * aff[c] + aff[64 + c]; }
        #pragma unroll
        for (int q = 0; q < 8; ++q) { int c = ch * 16 + 8 + q; t[spr][c] = bf2f(v1[q]) * aff[c] + aff[64 + c]; }
    }
    __syncthreads();
    {
        const int c = tid >> 2, sc = (tid & 3) * 16;
        #pragma unroll
        for (int i = 0; i < 4; ++i) {
            float4 w;
            w.x = t[sc + 4 * i][c]; w.y = t[sc + 4 * i + 1][c];
            w.z = t[sc + 4 * i + 2][c]; w.w = t[sc + 4 * i + 3][c];
            *(float4*)(out + (size_t)c * DHW1 + s0 + sc + 4 * i) = w;
        }
    }
}

// ---------------------------------------------------------------------------
// merged zeroing: PadA/PadB halo edges + trash plane, X0/Y0 same, stats
__global__ __launch_bounds__(256)
void zero_misc(short* __restrict__ PadA, short* __restrict__ PadB,
               short* __restrict__ X0, short* __restrict__ Y0, float* __restrict__ stats)
{
    const short8 z8 = {0, 0, 0, 0, 0, 0, 0, 0};
    int i = blockIdx.x * 256 + threadIdx.x;
    constexpr int T_F = 33 * 3104 + 76832;   // fine buffer: edges + trash plane (chunks)
    constexpr int T_X = 17 * 3136 + 40000;   // X0 (CPR=16)
    constexpr int T_Y = 17 * 1568 + 20000;   // Y0 (CPR=8)
    constexpr int TOT = 2 * T_F + T_X + T_Y + 128;
    if (i >= TOT) return;

    auto fine_off = [](int q) -> size_t {
        if (q < 33 * 3104) {
            int pl = q / 3104, e = q % 3104, p = e >> 3, c = e & 7;
            int y, x;
            if (p < 98) { y = 0; x = p; }
            else if (p < 196) { y = 97; x = p - 98; }
            else { int q2 = p - 196; y = 1 + (q2 >> 1); x = (q2 & 1) ? 97 : 0; }
            return ((size_t)pl * FP_PLPTS + y * 98 + x) * 64 + c * 8;
        }
        int q2 = q - 33 * 3104;
        return (size_t)32 * FP_PLPTS * 64 + (size_t)q2 * 8;
    };
    auto co_off = [](int q, int CPR) -> size_t {
        const int EPP = 196 * CPR;
        if (q < 17 * EPP) {
            int pl = q / EPP, e = q % EPP, p = e / CPR, c = e % CPR;
            int y, x;
            if (p < 50) { y = 0; x = p; }
            else if (p < 100) { y = 49; x = p - 50; }
            else { int r = p - 100; y = 1 + (r >> 1); x = (r & 1) ? 49 : 0; }
            return ((size_t)pl * CP_PLPTS + y * 50 + x) * (CPR * 8) + c * 8;
        }
        int q2 = q - 17 * EPP;
        return (size_t)16 * CP_PLPTS * (CPR * 8) + (size_t)q2 * 8;
    };

    if (i < T_F) { *(short8*)(PadA + fine_off(i)) = z8; return; } i -= T_F;
    if (i < T_F) { *(short8*)(PadB + fine_off(i)) = z8; return; } i -= T_F;
    if (i < T_X) { *(short8*)(X0 + co_off(i, 16)) = z8; return; } i -= T_X;
    if (i < T_Y) { *(short8*)(Y0 + co_off(i, 8)) = z8; return; } i -= T_Y;
    float4 zf = {0.f, 0.f, 0.f, 0.f};
    *(float4*)((char*)stats + (size_t)i * 16) = zf;
}

// ---------------------------------------------------------------------------
// Stage-A conv (CIN=128, coarse): R6-proven 2-phase counted-vmcnt kernel, MG=1.
template<int MG, int CIN, int KD, int KH, int KW, int PD, int PH, int PW,
         int GD, int GH, int GW, int OUTMODE, bool STATS>
__global__ __launch_bounds__(256, 2)
void convmm5(const short* __restrict__ A, const short* __restrict__ Wt,
             short* __restrict__ Out, float* __restrict__ stats)
{
    constexpr int MR   = 64 * MG;
    constexpr int KSZ  = KD * KH * KW;
    constexpr int PPW  = GW + 2;
    constexpr int PLP  = (GH + 2) * PPW;
    constexpr int HWg  = GH * GW;
    constexpr int CPR  = CIN / 8;
    constexpr int L2C  = (CIN == 64) ? 3 : 4;
    constexpr int RPI  = 64 / CPR;
    constexpr int ASZ  = MR * CIN * 2;
    constexpr int BSZ  = 64 * CIN * 2;
    constexpr int API  = ASZ / 4096;
    constexpr int BPI  = BSZ / 4096;
    constexpr int KCN  = CIN / 32;
    constexpr int S_IF = API + BPI;

    __shared__ char smem[2 * ASZ + 2 * BSZ];

    const int tid = threadIdx.x, lane = tid & 63, wave = tid >> 6;
    const int rl = lane & 15, kg = lane >> 4;

    const int nwg = gridDim.x;
    const int bid = blockIdx.x;
    const int bswz = (nwg & 7) ? bid : ((bid & 7) * (nwg >> 3) + (bid >> 3));
    const int row0 = bswz * MR;

    int zA[API], yxA[API], cofA[API];
    #pragma unroll
    for (int i = 0; i < API; ++i) {
        const int gi = wave * API + i;
        const int r = gi * RPI + (lane >> L2C);
        const int s = row0 + r;
        const int z = s / HWg; const int rm = s - z * HWg;
        const int y = rm / GW; const int x = rm - y * GW;
        zA[i] = z;
        yxA[i] = (y + 1) * PPW + (x + 1);
        cofA[i] = ((lane & (CPR - 1)) ^ (r & 7)) * 8;
    }
    int rB[BPI], cofB[BPI];
    #pragma unroll
    for (int i = 0; i < BPI; ++i) {
        const int gi = wave * BPI + i;
        const int r = gi * RPI + (lane >> L2C);
        rB[i] = r;
        cofB[i] = ((lane & (CPR - 1)) ^ (r & 7)) * 8;
    }

    auto stageA = [&](int bsel, int kd, int kh, int kw) {
        const int dyx = (kh - PH) * PPW + (kw - PW);
        #pragma unroll
        for (int i = 0; i < API; ++i) {
            int zp = zA[i] + (kd - PD);
            int pl = ((unsigned)zp < (unsigned)GD) ? zp : GD;
            const short* src = A + ((size_t)pl * PLP + yxA[i] + dyx) * CIN + cofA[i];
            void* dst = smem + bsel * ASZ + (wave * API + i) * 1024;
            gload16(src, dst);
        }
    };
    auto stageB = [&](int bsel, int t) {
        const short* wt = Wt + (size_t)t * 64 * CIN;
        #pragma unroll
        for (int i = 0; i < BPI; ++i) {
            const short* src = wt + rB[i] * CIN + cofB[i];
            void* dst = smem + 2 * ASZ + bsel * BSZ + (wave * BPI + i) * 1024;
            gload16(src, dst);
        }
    };

    f32x4 acc[MG][4];
    #pragma unroll
    for (int mg = 0; mg < MG; ++mg)
        #pragma unroll
        for (int ng = 0; ng < 4; ++ng)
            acc[mg][ng] = (f32x4){0.f, 0.f, 0.f, 0.f};

    auto comp = [&](int bsel) {
        const short* ab = (const short*)(smem + bsel * ASZ);
        const short* bb = (const short*)(smem + 2 * ASZ + bsel * BSZ);
        #pragma unroll
        for (int kc = 0; kc < KCN; ++kc) {
            short8 av[MG], bv[4];
            #pragma unroll
            for (int mg = 0; mg < MG; ++mg) {
                const int r = wave * (16 * MG) + mg * 16 + rl;
                const int c = (kc * 4 + kg) ^ (r & 7);
                av[mg] = *(const short8*)(ab + r * CIN + c * 8);
            }
            #pragma unroll
            for (int ng = 0; ng < 4; ++ng) {
                const int r = ng * 16 + rl;
                const int c = (kc * 4 + kg) ^ (r & 7);
                bv[ng] = *(const short8*)(bb + r * CIN + c * 8);
            }
            __builtin_amdgcn_s_setprio(1);
            #pragma unroll
            for (int mg = 0; mg < MG; ++mg)
                #pragma unroll
                for (int ng = 0; ng < 4; ++ng)
                    acc[mg][ng] = __builtin_amdgcn_mfma_f32_16x16x32_bf16(av[mg], bv[ng], acc[mg][ng], 0, 0, 0);
            __builtin_amdgcn_s_setprio(0);
        }
    };

    stageA(0, 0, 0, 0);
    stageB(0, 0);

    #pragma unroll
    for (int t = 0; t < KSZ; ++t) {
        const int cur = t & 1;
        if (t + 1 < KSZ) {
            const int t1 = t + 1;
            const int kd = t1 / (KH * KW), rm = t1 % (KH * KW);
            stageA(cur ^ 1, kd, rm / KW, rm % KW);
            stageB(cur ^ 1, t1);
            asm volatile("s_waitcnt vmcnt(%0)" :: "i"(S_IF) : "memory");
        } else {
            asm volatile("s_waitcnt vmcnt(0)" ::: "memory");
        }
        __builtin_amdgcn_s_barrier();
        __builtin_amdgcn_sched_barrier(0);
        comp(cur);
        asm volatile("s_waitcnt lgkmcnt(0)" ::: "memory");
        __builtin_amdgcn_sched_barrier(0);
        __builtin_amdgcn_s_barrier();
    }

    short (*tile)[64] = (short(*)[64])smem;
    float* red = (float*)(smem + 2 * ASZ);

    #pragma unroll
    for (int mg = 0; mg < MG; ++mg)
        #pragma unroll
        for (int ng = 0; ng < 4; ++ng)
            #pragma unroll
            for (int j = 0; j < 4; ++j) {
                float v = acc[mg][ng][j];
                if (STATS) v = (v >= 0.f) ? v : SLOPE * v;
                tile[wave * (16 * MG) + mg * 16 + kg * 4 + j][ng * 16 + rl] = f2bf(v);
            }
    __syncthreads();

    #pragma unroll
    for (int i = 0; i < MR / 32; ++i) {
        const int chunk = i * 256 + tid;
        const int r = chunk >> 3, cc = (chunk & 7) * 8;
        const int s = row0 + r;
        size_t o;
        if (OUTMODE == 0)      o = (size_t)s * 64 + cc;
        else if (OUTMODE == 1) o = (size_t)pidx_fine(s) * 64 + cc;
        else                   o = (size_t)pidx_coarse(s) * 64 + cc;
        *(short8*)(Out + o) = *(const short8*)&tile[r][cc];
    }

    if (STATS) {
        float s1 = 0.f, s2 = 0.f;
        const int col = tid & 63, rg = tid >> 6;
        #pragma unroll 4
        for (int r = rg * (MR / 4); r < (rg + 1) * (MR / 4); ++r) {
            float v = bf2f(tile[r][col]); s1 += v; s2 += v * v;
        }
        red[rg * 64 + col] = s1;
        red[256 + rg * 64 + col] = s2;
        __syncthreads();
        if (tid < 64) {
            float a = red[tid] + red[64 + tid] + red[128 + tid] + red[192 + tid];
            float b = red[256 + tid] + red[320 + tid] + red[384 + tid] + red[448 + tid];
            atomicAdd(&stats[tid], a);
            atomicAdd(&stats[64 + tid], b);
        }
    }
}

// ---------------------------------------------------------------------------
// Fine convs (C/D/E): 2-wave block, 192-row tile = exactly two x-rows.
// A staged per (kd,kh) group as TWO COMPLETE padded rows (208 pts incl pad),
// double-buffered; kw=+-1 served by in-row zero halos. B per-tap dbuf.
// mg=6 per wave (96x64 wave tile). Counted vmcnt; 2 barriers/phase; setprio.
template<int KD, int KH, int PD, int PH, int OUTMODE, bool STATS>
__global__ __launch_bounds__(128, 1)
void convmm7(const short* __restrict__ A, const short* __restrict__ Wt,
             short* __restrict__ Out, float* __restrict__ stats)
{
    constexpr int KSZ = KD * KH * 3, NG = KD * KH;
    constexpr int PLP = FP_PLPTS;
    constexpr int ABYTES = 208 * 128;     // 26624
    constexpr int BBYTES = 8192;
    __shared__ __align__(16) char smem[2 * ABYTES + 2 * BBYTES];   // 69632

    const int tid = threadIdx.x, lane = tid & 63, wave = tid >> 6;  // wave 0..1
    const int rl = lane & 15, kg = lane >> 4;

    const int nwg = gridDim.x, bid = blockIdx.x;
    const int bswz = (bid & 7) * (nwg >> 3) + (bid >> 3);
    const int s0 = bswz * 192;
    const int z0 = s0 / HW1;                 // 9216/192=48 -> never straddles z
    const int y0 = (s0 - z0 * HW1) / 96;     // even, rows aligned

    const int ptl = lane >> 3;               // pt offset within 1KB instr
    const int csl = (lane & 7) ^ ptl;        // XOR-swizzled source chunk

    auto stageA = [&](int bsel, int g) {
        const int kd = g / KH, kh = g % KH;
        const int zp = z0 + kd - PD;
        const int pl = ((unsigned)zp < 32u) ? zp : 32;   // trash plane (zeros)
        const int ys = y0 + kh - PH;                     // first source row
        const size_t base = (size_t)pl * PLP + (size_t)(ys + 1) * 98;
        #pragma unroll
        for (int i = 0; i < 13; ++i) {
            const int ii = wave * 13 + i;
            const short* src = A + (base + ii * 8 + ptl) * 64 + csl * 8;
            gload16(src, smem + bsel * ABYTES + ii * 1024);
        }
    };
    auto stageB = [&](int bsel, int t) {
        const short* wt = Wt + (size_t)t * 4096;
        #pragma unroll
        for (int i = 0; i < 4; ++i) {
            const int ii = wave * 4 + i;
            const short* src = wt + (ii * 8 + ptl) * 64 + csl * 8;
            gload16(src, smem + 2 * ABYTES + bsel * BBYTES + ii * 1024);
        }
    };

    f32x4 acc[6][4];
    #pragma unroll
    for (int mg = 0; mg < 6; ++mg)
        #pragma unroll
        for (int ng = 0; ng < 4; ++ng)
            acc[mg][ng] = (f32x4){0.f, 0.f, 0.f, 0.f};

    const int jb = wave * 98 + rl;           // segment row base (+ mg*16 + kw)

    stageA(0, 0);
    stageB(0, 0);

    #pragma unroll
    for (int t = 0; t < KSZ; ++t) {
        const int g = t / 3, kw = t % 3;
        if (kw == 0 && g + 1 < NG) stageA((g + 1) & 1, g + 1);
        if (t + 1 < KSZ) stageB((t + 1) & 1, t + 1);
        if (t == KSZ - 1)
            asm volatile("s_waitcnt vmcnt(0)" ::: "memory");
        else if (kw == 0 && g + 1 < NG)
            asm volatile("s_waitcnt vmcnt(17)" ::: "memory");
        else
            asm volatile("s_waitcnt vmcnt(4)" ::: "memory");
        __builtin_amdgcn_s_barrier();
        __builtin_amdgcn_sched_barrier(0);

        const char* ab = smem + (g & 1) * ABYTES;
        const char* bb = smem + 2 * ABYTES + (t & 1) * BBYTES;
        #pragma unroll
        for (int kc = 0; kc < 2; ++kc) {
            short8 bv[4], av[6];
            #pragma unroll
            for (int ng = 0; ng < 4; ++ng) {
                const int row = ng * 16 + rl;
                bv[ng] = *(const short8*)(bb + row * 128 + (((kc * 4 + kg) ^ (rl & 7)) << 4));
            }
            #pragma unroll
            for (int mg = 0; mg < 6; ++mg) {
                const int j = jb + mg * 16 + kw;
                av[mg] = *(const short8*)(ab + j * 128 + (((kc * 4 + kg) ^ (j & 7)) << 4));
            }
            __builtin_amdgcn_s_setprio(1);
            #pragma unroll
            for (int mg = 0; mg < 6; ++mg)
                #pragma unroll
                for (int ng = 0; ng < 4; ++ng)
                    acc[mg][ng] = __builtin_amdgcn_mfma_f32_16x16x32_bf16(av[mg], bv[ng], acc[mg][ng], 0, 0, 0);
            __builtin_amdgcn_s_setprio(0);
        }
        asm volatile("s_waitcnt lgkmcnt(0)" ::: "memory");
        __builtin_amdgcn_sched_barrier(0);
        __builtin_amdgcn_s_barrier();
    }

    // epilogue: tile [192][64] aliases smem; red after it
    short (*tile)[64] = (short(*)[64])smem;
    float* red = (float*)(smem + 192 * 64 * 2);

    #pragma unroll
    for (int mg = 0; mg < 6; ++mg)
        #pragma unroll
        for (int ng = 0; ng < 4; ++ng)
            #pragma unroll
            for (int j = 0; j < 4; ++j) {
                float v = acc[mg][ng][j];
                if (STATS) v = (v >= 0.f) ? v : SLOPE * v;
                tile[wave * 96 + mg * 16 + kg * 4 + j][ng * 16 + rl] = f2bf(v);
            }
    __syncthreads();

    #pragma unroll
    for (int i = 0; i < 12; ++i) {
        const int chunk = i * 128 + tid;
        const int r = chunk >> 3, cc = (chunk & 7) * 8;
        const int s = s0 + r;
        size_t o;
        if (OUTMODE == 0) o = (size_t)s * 64 + cc;
        else              o = (size_t)pidx_fine(s) * 64 + cc;
        *(short8*)(Out + o) = *(const short8*)&tile[r][cc];
    }

    if (STATS) {
        float s1 = 0.f, s2 = 0.f;
        const int col = tid & 63, rg = tid >> 6;   // 0..1
        #pragma unroll 4
        for (int r = rg * 96; r < rg * 96 + 96; ++r) {
            float v = bf2f(tile[r][col]); s1 += v; s2 += v * v;
        }
        red[rg * 64 + col] = s1;
        red[128 + rg * 64 + col] = s2;
        __syncthreads();
        if (tid < 64) {
            atomicAdd(&stats[tid], red[tid] + red[64 + tid]);
            atomicAdd(&stats[64 + tid], red[128 + tid] + red[192 + tid]);
        }
    }
}

// ---------------------------------------------------------------------------
// Transposed conv by output-parity class (R6-proven).
__global__ __launch_bounds__(256, 2)
void tconv_cls(const short* __restrict__ Y, const short* __restrict__ Wt,
               const short* __restrict__ SK, short* __restrict__ Out)
{
    const int cls = blockIdx.y;
    const int pz = (cls >> 2) & 1, py = (cls >> 1) & 1, px = cls & 1;
    const int tid = threadIdx.x, lane = tid & 63, wave = tid >> 6;
    const int rl = lane & 15, kg = lane >> 4;
    const int row0 = blockIdx.x * 256;

    int zin0[4], zin1[4];
    #pragma unroll
    for (int mg = 0; mg < 4; ++mg) {
        int s = row0 + wave * 64 + mg * 16 + rl;
        int zc = s / HW0; int r = s - zc * HW0; int yc = r / W0; int xc = r - yc * W0;
        int ib = ((yc + 1) * 50 + (xc + 1)) * 64 + kg * 8;
        zin0[mg] = zc * (CP_PLPTS * 64) + ib;
        zin1[mg] = ((zc + 1 < 16) ? zc + 1 : 16) * (CP_PLPTS * 64) + ib;
    }
    const int boff = rl * 64 + kg * 8;

    f32x4 acc[4][4];
    #pragma unroll
    for (int mg = 0; mg < 4; ++mg)
        #pragma unroll
        for (int ng = 0; ng < 4; ++ng)
            acc[mg][ng] = (f32x4){0.f, 0.f, 0.f, 0.f};

    for (int a = 0; a <= pz; ++a) {
        const int kd = pz ? 2 * a : 1;
        for (int b = 0; b <= py; ++b) {
            const int kh = py ? 2 * b : 1;
            for (int c = 0; c <= px; ++c) {
                const int kw = px ? 2 * c : 1;
                const int t = kd * 9 + kh * 3 + kw;
                const int dlt = (b * 50 + c) * 64;
                int ao[4];
                #pragma unroll
                for (int mg = 0; mg < 4; ++mg)
                    ao[mg] = (a ? zin1[mg] : zin0[mg]) + dlt;
                #pragma unroll
                for (int kc = 0; kc < 2; ++kc) {
                    short8 av[4], bv[4];
                    #pragma unroll
                    for (int mg = 0; mg < 4; ++mg)
                        av[mg] = *(const short8*)(Y + ao[mg] + kc * 32);
                    #pragma unroll
                    for (int ng = 0; ng < 4; ++ng)
                        bv[ng] = *(const short8*)(Wt + (t * 64 + ng * 16) * 64 + boff + kc * 32);
                    #pragma unroll
                    for (int mg = 0; mg < 4; ++mg)
                        #pragma unroll
                        for (int ng = 0; ng < 4; ++ng)
                            acc[mg][ng] = __builtin_amdgcn_mfma_f32_16x16x32_bf16(av[mg], bv[ng], acc[mg][ng], 0, 0, 0);
                }
            }
        }
    }

    __shared__ short tile[256][72];
    #pragma unroll
    for (int mg = 0; mg < 4; ++mg)
        #pragma unroll
        for (int ng = 0; ng < 4; ++ng)
            #pragma unroll
            for (int j = 0; j < 4; ++j)
                tile[wave * 64 + mg * 16 + kg * 4 + j][ng * 16 + rl] = f2bf(acc[mg][ng][j]);
    __syncthreads();

    #pragma unroll
    for (int i = 0; i < 8; ++i) {
        int chunk = i * 256 + tid;
        int r = chunk >> 3, cc = (chunk & 7) * 8;
        int sl = row0 + r;
        int zc = sl / HW0; int rr = sl - zc * HW0; int yc = rr / W0; int xc = rr - yc * W0;
        int z = 2 * zc + pz, y = 2 * yc + py, x = 2 * xc + px;
        size_t so = (size_t)((z * H1 + y) * W1_ + x) * 64 + cc;
        size_t po = (size_t)(z * FP_PLPTS + (y + 1) * 98 + (x + 1)) * 64 + cc;
        short8 v = *(const short8*)&tile[r][cc];
        short8 skv = *(const short8*)(SK + so);
        short8 o;
        #pragma unroll
        for (int q = 0; q < 8; ++q) o[q] = f2bf(bf2f(v[q]) + bf2f(skv[q]));
        *(short8*)(Out + po) = o;
    }
}

// ---------------------------------------------------------------------------
extern "C" void kernel_launch(void* const* d_in, const int* in_sizes, int n_in,
                              void* d_out, int out_size, void* d_ws, size_t ws_size,
                              hipStream_t stream)
{
    const float* x       = (const float*)d_in[0];
    const float* skip    = (const float*)d_in[1];
    const float* w_trans = (const float*)d_in[2];
    const float* g_t     = (const float*)d_in[3];
    const float* b_t     = (const float*)d_in[4];
    const float* w_up    = (const float*)d_in[5];
    const float* w1      = (const float*)d_in[6];
    const float* g1      = (const float*)d_in[7];
    const float* b1      = (const float*)d_in[8];
    const float* w2      = (const float*)d_in[9];
    const float* g2      = (const float*)d_in[10];
    const float* b2      = (const float*)d_in[11];
    const float* w3      = (const float*)d_in[12];
    const float* g3      = (const float*)d_in[13];
    const float* b3      = (const float*)d_in[14];
    float* out = (float*)d_out;

    char* ws = (char*)d_ws;
    short* PadA = (short*)ws;
    short* PadB = (short*)(ws + (size_t)FP_ELEMS * 2);
    float* stats = (float*)(ws + (size_t)FP_ELEMS * 4);

    float* st0 = stats;       float* af0 = stats + 512;
    float* st1 = stats + 128; float* af1 = stats + 512 + 128;
    float* st2 = stats + 256; float* af2 = stats + 512 + 256;
    float* st3 = stats + 384; float* af3 = stats + 512 + 384;

    char* ob = (char*)d_out;
    short* X0  = (short*)ob;                       // coarse padded 128ch
    short* Y0  = (short*)(ob + 10880000);          // coarse padded 64ch
    short* SKb = (short*)(ob + 16320000);          // compact fine skip
    short* wt_t  = (short*)(ob + 54068736);
    short* wt_up = wt_t + 221184;
    short* wt_1  = wt_up + 110592;
    short* wt_2  = wt_1 + 36864;
    short* wt_3  = wt_2 + 36864;

    // merged zeroing (halo edges + trash planes + stats)
    zero_misc<<<(2 * (33 * 3104 + 76832) + (17 * 3136 + 40000) + (17 * 1568 + 20000) + 128 + 255) / 256,
               256, 0, stream>>>(PadA, PadB, X0, Y0, stats);

    // merged weight repacks
    prep_all<<<2016, 256, 0, stream>>>(w_trans, w_up, w1, w2, w3,
                                       wt_t, wt_up, wt_1, wt_2, wt_3);

    // input transposes
    to_cl_pad128<<<dim3(DHW0 / 64, 2), 256, 0, stream>>>(x, X0);
    to_cl_bf16<<<DHW1 / 64, 256, 0, stream>>>(skip, SKb, DHW1);

    // stage A: subm 3x3x3 CIN=128 coarse -> Y0pad (raw lrelu) + stats
    convmm5<1, 128, 3, 3, 3, 1, 1, 1, 16, 48, 48, 2, true>
        <<<DHW0 / 64, 256, 0, stream>>>(X0, wt_t, Y0, st0);
    finalize_stats<<<1, 64, 0, stream>>>(st0, g_t, b_t, 1.f / DHW0, af0);
    affine_pad<2><<<(DHW0 * 8 + 255) / 256, 256, 0, stream>>>(Y0, af0, DHW0 * 8);

    // stage B: transposed conv by parity class + skip -> PadA
    tconv_cls<<<dim3(DHW0 / 256, 8), 256, 0, stream>>>(Y0, wt_up, SKb, PadA);

    // stage C: conv (1,3,3) pad (0,1,1) -> PadB + stats  [KD=1,KH=3,PD=0,PH=1]
    convmm7<1, 3, 0, 1, 1, true>
        <<<DHW1 / 192, 128, 0, stream>>>(PadA, wt_1, PadB, st1);
    finalize_stats<<<1, 64, 0, stream>>>(st1, g1, b1, 1.f / DHW1, af1);
    affine_pad<1><<<(DHW1 * 8 + 255) / 256, 256, 0, stream>>>(PadB, af1, DHW1 * 8);

    // stage D: conv (3,1,3) pad (1,0,1) -> PadA + stats  [KD=3,KH=1,PD=1,PH=0]
    convmm7<3, 1, 1, 0, 1, true>
        <<<DHW1 / 192, 128, 0, stream>>>(PadB, wt_2, PadA, st2);
    finalize_stats<<<1, 64, 0, stream>>>(st2, g2, b2, 1.f / DHW1, af2);
    affine_pad<1><<<(DHW1 * 8 + 255) / 256, 256, 0, stream>>>(PadA, af2, DHW1 * 8);

    // stage E: conv (3,3,3) pad 1 -> PadB COMPACT + stats [KD=3,KH=3,PD=1,PH=1]
    convmm7<3, 3, 1, 1, 0, true>
        <<<DHW1 / 192, 128, 0, stream>>>(PadA, wt_3, PadB, st3);
    finalize_stats<<<1, 64, 0, stream>>>(st3, g3, b3, 1.f / DHW1, af3);

    // final: aff3 + transpose to NCDHW fp32
    final_out<<<DHW1 / 64, 256, 0, stream>>>(PadB, out, af3);
}